// Round 4
// baseline (77.240 us; speedup 1.0000x reference)
//
#include <hip/hip_runtime.h>
#include <hip/hip_bf16.h>

#define NMOV 32768
#define LW 15
#define DIM 256
#define NVOC 27
#define NR 405       // NVOC * LW distinct (letter, position) rows
#define GSH 408      // row stride of H in float2 units
#define MPB 8        // moves per block in moves_kernel

__device__ __forceinline__ float b2f(unsigned short u) {
    return __uint_as_float(((unsigned int)u) << 16);
}

// pair index p -> (l<<4 | m), l >= m, p = l(l+1)/2 + m
__device__ const unsigned char PAIR_LUT[120] = {
    0x00,
    0x10,0x11,
    0x20,0x21,0x22,
    0x30,0x31,0x32,0x33,
    0x40,0x41,0x42,0x43,0x44,
    0x50,0x51,0x52,0x53,0x54,0x55,
    0x60,0x61,0x62,0x63,0x64,0x65,0x66,
    0x70,0x71,0x72,0x73,0x74,0x75,0x76,0x77,
    0x80,0x81,0x82,0x83,0x84,0x85,0x86,0x87,0x88,
    0x90,0x91,0x92,0x93,0x94,0x95,0x96,0x97,0x98,0x99,
    0xA0,0xA1,0xA2,0xA3,0xA4,0xA5,0xA6,0xA7,0xA8,0xA9,0xAA,
    0xB0,0xB1,0xB2,0xB3,0xB4,0xB5,0xB6,0xB7,0xB8,0xB9,0xBA,0xBB,
    0xC0,0xC1,0xC2,0xC3,0xC4,0xC5,0xC6,0xC7,0xC8,0xC9,0xCA,0xCB,0xCC,
    0xD0,0xD1,0xD2,0xD3,0xD4,0xD5,0xD6,0xD7,0xD8,0xD9,0xDA,0xDB,0xDC,0xDD,
    0xE0,0xE1,0xE2,0xE3,0xE4,0xE5,0xE6,0xE7,0xE8,0xE9,0xEA,0xEB,0xEC,0xED,0xEE
};

// ---------------------------------------------------------------------------
// Kernel 1: QT/KT/VT tables [405][256], split by (letter, pos-group, matrix).
// 405 blocks = 27 x 5 x 3; 256 threads (one per output dim d).
// ---------------------------------------------------------------------------
__global__ __launch_bounds__(256) void qkv_tables(
    const float* __restrict__ le, const float* __restrict__ pos,
    const float* __restrict__ Wq, const float* __restrict__ bq,
    const float* __restrict__ Wk, const float* __restrict__ bk,
    const float* __restrict__ Wv, const float* __restrict__ bv,
    float* __restrict__ QT, float* __restrict__ KT,
    __hip_bfloat16* __restrict__ VT)
{
    const int b   = blockIdx.x;
    const int c   = b / 15;
    const int rem = b % 15;
    const int lg  = rem / 3;
    const int mat = rem % 3;
    const int d   = threadIdx.x;

    const float* W  = (mat == 0) ? Wq : (mat == 1) ? Wk : Wv;
    const float* bb = (mat == 0) ? bq : (mat == 1) ? bk : bv;

    __shared__ float e[3][DIM];
    const float lv = le[c * DIM + d];
    #pragma unroll
    for (int k = 0; k < 3; ++k)
        e[k][d] = lv + pos[(lg * 3 + k) * DIM + d];
    __syncthreads();

    float acc[3];
    const float bias = bb[d];
    #pragma unroll
    for (int k = 0; k < 3; ++k) acc[k] = bias;

    const float4* w4 = (const float4*)(W + d * DIM);
    #pragma unroll 8
    for (int j4 = 0; j4 < DIM / 4; ++j4) {
        float4 w = w4[j4];
        #pragma unroll
        for (int k = 0; k < 3; ++k) {
            float4 e4 = *(const float4*)&e[k][j4 * 4];
            acc[k] += e4.x * w.x + e4.y * w.y + e4.z * w.z + e4.w * w.w;
        }
    }
    #pragma unroll
    for (int k = 0; k < 3; ++k) {
        int r = c * LW + lg * 3 + k;
        if (mat == 0)      QT[r * DIM + d] = acc[k];
        else if (mat == 1) KT[r * DIM + d] = acc[k];
        else               VT[r * DIM + d] = __float2bfloat16(acc[k]);
    }
}

// ---------------------------------------------------------------------------
// Kernel 2: H[i][j] = { G[i][j], G[j][i] },  G[i][j] = QT[i,:].KT[j,:].
// Tile pairs (bi <= bj), 351 blocks, 16x16 tiles, BK=64.
// ---------------------------------------------------------------------------
__global__ __launch_bounds__(256) void h_matrix(
    const float* __restrict__ QT, const float* __restrict__ KT,
    float2* __restrict__ H)
{
    __shared__ float Qi[16][68], Ki[16][68], Qj[16][68], Kj[16][68];

    int rem = blockIdx.x, bi = 0, cnt = 26;
    while (rem >= cnt) { rem -= cnt; ++bi; --cnt; }
    const int bj = bi + rem;
    const int i0 = bi * 16, j0 = bj * 16;
    const int t = threadIdx.x;
    const int ti = t >> 4, tj = t & 15;

    float acc_ij = 0.f, acc_ji = 0.f;

    for (int k0 = 0; k0 < DIM; k0 += 64) {
        #pragma unroll
        for (int s = 0; s < 4; ++s) {
            int slot = s * 256 + t;          // 1024 float4 slots
            int tile = slot >> 8;            // 0:Qi 1:Ki 2:Qj 3:Kj
            int r    = (slot >> 4) & 15;
            int c4   = slot & 15;
            int grow = (tile < 2) ? (i0 + r) : (j0 + r);
            const float* src = (tile == 0 || tile == 2) ? QT : KT;
            float4 v = (grow < NR)
                ? *(const float4*)&src[grow * DIM + k0 + c4 * 4]
                : make_float4(0.f, 0.f, 0.f, 0.f);
            float* dst = (tile == 0) ? &Qi[r][c4 * 4]
                       : (tile == 1) ? &Ki[r][c4 * 4]
                       : (tile == 2) ? &Qj[r][c4 * 4] : &Kj[r][c4 * 4];
            *(float4*)dst = v;
        }
        __syncthreads();
        #pragma unroll 4
        for (int k = 0; k < 64; k += 4) {
            float4 qi = *(const float4*)&Qi[ti][k];
            float4 kj = *(const float4*)&Kj[tj][k];
            float4 qj = *(const float4*)&Qj[ti][k];
            float4 ki = *(const float4*)&Ki[tj][k];
            acc_ij += qi.x * kj.x + qi.y * kj.y + qi.z * kj.z + qi.w * kj.w;
            acc_ji += qj.x * ki.x + qj.y * ki.y + qj.z * ki.z + qj.w * ki.w;
        }
        __syncthreads();
    }

    Qi[ti][tj] = acc_ij;
    Ki[ti][tj] = acc_ji;
    __syncthreads();
    const float t_ij = Qi[tj][ti];   // G[i0+tj][j0+ti]
    const float t_ji = Ki[tj][ti];   // G[j0+tj][i0+ti]

    const int i1 = i0 + ti, j1 = j0 + tj;
    if (i1 < NR && j1 < NR) H[i1 * GSH + j1] = make_float2(acc_ij, t_ji);
    const int i2 = j0 + ti, j2 = i0 + tj;
    if (i2 < NR && j2 < NR) H[i2 * GSH + j2] = make_float2(acc_ji, t_ij);
}

// ---------------------------------------------------------------------------
// Kernel 3: fully wave-synchronous per-move pipeline — ZERO __syncthreads.
// 4096 blocks x 256 threads, 8 moves per block; move mv owned by half-wave mv,
// so every LDS producer/consumer pair lives in the same wave:
//   rIdx load -> pair gathers -> row softmax -> colsum  (half-wave mv)
//   phase 2: wave w consumes moves 2w, 2w+1 (its own half-waves).
// wave_barrier() = compiler fence only; HW DS ops are in-order per wave.
// ---------------------------------------------------------------------------
__global__ __launch_bounds__(256, 8) void moves_kernel(
    const int* __restrict__ words, const int* __restrict__ rowsI,
    const int* __restrict__ colsI, const int* __restrict__ dirsI,
    const int* __restrict__ scoresI,
    const float2* __restrict__ H, const __hip_bfloat16* __restrict__ VT,
    const float* __restrict__ row_emb, const float* __restrict__ col_emb,
    const float* __restrict__ dir_emb, const float* __restrict__ score_emb,
    float* __restrict__ out)
{
    __shared__ float S[MPB][LW][17];     // 15x15 score matrix per move (padded)
    __shared__ int   rIdx[MPB][16];      // row indices per move
    __shared__ float csum[MPB][16];      // per-move column sums
    const int base = blockIdx.x * MPB;
    const int t = threadIdx.x;
    const int mv = t >> 5;               // half-wave id = move slot
    const int j  = t & 31;

    // rIdx: lanes j<15 of half-wave mv load move mv's own indices
    if (j < LW)
        rIdx[mv][j] = words[(base + mv) * LW + j] * LW + j;
    __builtin_amdgcn_wave_barrier();

    // -------- phase 1: 120 pair gathers per move over 32 lanes
    #pragma unroll
    for (int k = 0; k < 4; ++k) {
        int p = j + 32 * k;
        if (p < 120) {
            int lm = PAIR_LUT[p];
            int l = lm >> 4, m = lm & 15;
            int rl = rIdx[mv][l], rm = rIdx[mv][m];
            float2 hv = H[(size_t)rl * GSH + rm];
            S[mv][l][m] = hv.x;          // G[rl][rm] = S[l][m]
            S[mv][m][l] = hv.y;          // G[rm][rl] = S[m][l]
        }
    }
    __builtin_amdgcn_wave_barrier();

    // -------- phase 1b: row softmax (lane j handles row j of move mv)
    if (j < LW) {
        float s[LW];
        #pragma unroll
        for (int m = 0; m < LW; ++m) s[m] = S[mv][j][m];
        float mx = s[0];
        #pragma unroll
        for (int m = 1; m < LW; ++m) mx = fmaxf(mx, s[m]);
        float sum = 0.f;
        #pragma unroll
        for (int m = 0; m < LW; ++m) { s[m] = __expf(s[m] - mx); sum += s[m]; }
        float inv = 1.0f / sum;
        #pragma unroll
        for (int m = 0; m < LW; ++m) S[mv][j][m] = s[m] * inv;
    }
    __builtin_amdgcn_wave_barrier();

    // -------- column sums (lane j handles column j of move mv)
    if (j < LW) {
        float acc = 0.f;
        #pragma unroll
        for (int l = 0; l < LW; ++l) acc += S[mv][l][j];
        csum[mv][j] = acc;
    }
    __builtin_amdgcn_wave_barrier();

    // -------- phase 2: wave wv handles moves 2wv, 2wv+1 (wave-local data)
    const int wv = t >> 6;
    const int d0 = (t & 63) * 4;
    #pragma unroll
    for (int s2 = 0; s2 < 2; ++s2) {
        const int i = wv * 2 + s2;
        const int n = base + i;
        float wx = 0.f, wy = 0.f, wz = 0.f, ww = 0.f;
        #pragma unroll
        for (int m = 0; m < LW; ++m) {
            float c = csum[i][m];
            int r = rIdx[i][m];
            ushort4 vv = *(const ushort4*)((const unsigned short*)VT + (size_t)r * DIM + d0);
            wx += c * b2f(vv.x); wy += c * b2f(vv.y);
            wz += c * b2f(vv.z); ww += c * b2f(vv.w);
        }
        // uniform-address meta loads (1 line each, broadcast)
        float4 re = *(const float4*)&row_emb[rowsI[n] * DIM + d0];
        float4 ce = *(const float4*)&col_emb[colsI[n] * DIM + d0];
        float4 de = *(const float4*)&dir_emb[dirsI[n] * DIM + d0];
        float4 se = *(const float4*)&score_emb[min(scoresI[n], 99) * DIM + d0];
        float4 res;
        res.x = 2.f * wx + re.x + ce.x + de.x + se.x;
        res.y = 2.f * wy + re.y + ce.y + de.y + se.y;
        res.z = 2.f * wz + re.z + ce.z + de.z + se.z;
        res.w = 2.f * ww + re.w + ce.w + de.w + se.w;
        *(float4*)&out[(size_t)n * DIM + d0] = res;
    }
}

extern "C" void kernel_launch(void* const* d_in, const int* in_sizes, int n_in,
                              void* d_out, int out_size, void* d_ws, size_t ws_size,
                              hipStream_t stream)
{
    const int*   words      = (const int*)d_in[0];
    const int*   rowsI      = (const int*)d_in[1];
    const int*   colsI      = (const int*)d_in[2];
    const int*   dirsI      = (const int*)d_in[3];
    const int*   scoresI    = (const int*)d_in[4];
    const float* letter_emb = (const float*)d_in[5];
    const float* positional = (const float*)d_in[6];
    const float* Wq         = (const float*)d_in[7];
    const float* bq         = (const float*)d_in[8];
    const float* Wk         = (const float*)d_in[9];
    const float* bk         = (const float*)d_in[10];
    const float* Wv         = (const float*)d_in[11];
    const float* bv         = (const float*)d_in[12];
    const float* row_emb    = (const float*)d_in[13];
    const float* col_emb    = (const float*)d_in[14];
    const float* dir_emb    = (const float*)d_in[15];
    const float* score_emb  = (const float*)d_in[16];
    float* out = (float*)d_out;

    // workspace (bytes): QT f32[405*256] | KT f32[405*256] | H f2[405*408] | VT bf16[405*256]
    float*  QT = (float*)d_ws;
    float*  KT = QT + NR * DIM;
    float2* Hm = (float2*)(KT + NR * DIM);
    __hip_bfloat16* VT = (__hip_bfloat16*)((char*)Hm + (size_t)NR * GSH * sizeof(float2));

    qkv_tables<<<405, 256, 0, stream>>>(letter_emb, positional, Wq, bq, Wk, bk,
                                        Wv, bv, QT, KT, VT);
    h_matrix<<<351, 256, 0, stream>>>(QT, KT, Hm);
    moves_kernel<<<NMOV / MPB, 256, 0, stream>>>(words, rowsI, colsI, dirsI,
                                                 scoresI, Hm, VT, row_emb,
                                                 col_emb, dir_emb, score_emb,
                                                 out);
}

// Round 5
// 68.651 us; speedup vs baseline: 1.1251x; 1.1251x over previous
//
#include <hip/hip_runtime.h>
#include <hip/hip_bf16.h>

#define NMOV 32768
#define LW 15
#define DIM 256
#define NVOC 27
#define NR 405       // NVOC * LW distinct (letter, position) rows
#define GSH 408      // row stride of H in float2 units
#define MPB 8        // moves per block in moves_kernel

__device__ __forceinline__ float b2f(unsigned short u) {
    return __uint_as_float(((unsigned int)u) << 16);
}

// pair index p -> (l<<4 | m), l >= m, p = l(l+1)/2 + m
__device__ const unsigned char PAIR_LUT[120] = {
    0x00,
    0x10,0x11,
    0x20,0x21,0x22,
    0x30,0x31,0x32,0x33,
    0x40,0x41,0x42,0x43,0x44,
    0x50,0x51,0x52,0x53,0x54,0x55,
    0x60,0x61,0x62,0x63,0x64,0x65,0x66,
    0x70,0x71,0x72,0x73,0x74,0x75,0x76,0x77,
    0x80,0x81,0x82,0x83,0x84,0x85,0x86,0x87,0x88,
    0x90,0x91,0x92,0x93,0x94,0x95,0x96,0x97,0x98,0x99,
    0xA0,0xA1,0xA2,0xA3,0xA4,0xA5,0xA6,0xA7,0xA8,0xA9,0xAA,
    0xB0,0xB1,0xB2,0xB3,0xB4,0xB5,0xB6,0xB7,0xB8,0xB9,0xBA,0xBB,
    0xC0,0xC1,0xC2,0xC3,0xC4,0xC5,0xC6,0xC7,0xC8,0xC9,0xCA,0xCB,0xCC,
    0xD0,0xD1,0xD2,0xD3,0xD4,0xD5,0xD6,0xD7,0xD8,0xD9,0xDA,0xDB,0xDC,0xDD,
    0xE0,0xE1,0xE2,0xE3,0xE4,0xE5,0xE6,0xE7,0xE8,0xE9,0xEA,0xEB,0xEC,0xED,0xEE
};

// ---------------------------------------------------------------------------
// Kernel 1: QT/KT/VT tables [405][256], split by (letter, pos-group, matrix).
// 405 blocks = 27 x 5 x 3; 256 threads (one per output dim d).
// ---------------------------------------------------------------------------
__global__ __launch_bounds__(256) void qkv_tables(
    const float* __restrict__ le, const float* __restrict__ pos,
    const float* __restrict__ Wq, const float* __restrict__ bq,
    const float* __restrict__ Wk, const float* __restrict__ bk,
    const float* __restrict__ Wv, const float* __restrict__ bv,
    float* __restrict__ QT, float* __restrict__ KT,
    __hip_bfloat16* __restrict__ VT)
{
    const int b   = blockIdx.x;
    const int c   = b / 15;
    const int rem = b % 15;
    const int lg  = rem / 3;
    const int mat = rem % 3;
    const int d   = threadIdx.x;

    const float* W  = (mat == 0) ? Wq : (mat == 1) ? Wk : Wv;
    const float* bb = (mat == 0) ? bq : (mat == 1) ? bk : bv;

    __shared__ float e[3][DIM];
    const float lv = le[c * DIM + d];
    #pragma unroll
    for (int k = 0; k < 3; ++k)
        e[k][d] = lv + pos[(lg * 3 + k) * DIM + d];
    __syncthreads();

    float acc[3];
    const float bias = bb[d];
    #pragma unroll
    for (int k = 0; k < 3; ++k) acc[k] = bias;

    const float4* w4 = (const float4*)(W + d * DIM);
    #pragma unroll 8
    for (int j4 = 0; j4 < DIM / 4; ++j4) {
        float4 w = w4[j4];
        #pragma unroll
        for (int k = 0; k < 3; ++k) {
            float4 e4 = *(const float4*)&e[k][j4 * 4];
            acc[k] += e4.x * w.x + e4.y * w.y + e4.z * w.z + e4.w * w.w;
        }
    }
    #pragma unroll
    for (int k = 0; k < 3; ++k) {
        int r = c * LW + lg * 3 + k;
        if (mat == 0)      QT[r * DIM + d] = acc[k];
        else if (mat == 1) KT[r * DIM + d] = acc[k];
        else               VT[r * DIM + d] = __float2bfloat16(acc[k]);
    }
}

// ---------------------------------------------------------------------------
// Kernel 2: H[i][j] = { G[i][j], G[j][i] },  G[i][j] = QT[i,:].KT[j,:].
// Tile pairs (bi <= bj), 351 blocks, 16x16 tiles, BK=64.
// ---------------------------------------------------------------------------
__global__ __launch_bounds__(256) void h_matrix(
    const float* __restrict__ QT, const float* __restrict__ KT,
    float2* __restrict__ H)
{
    __shared__ float Qi[16][68], Ki[16][68], Qj[16][68], Kj[16][68];

    int rem = blockIdx.x, bi = 0, cnt = 26;
    while (rem >= cnt) { rem -= cnt; ++bi; --cnt; }
    const int bj = bi + rem;
    const int i0 = bi * 16, j0 = bj * 16;
    const int t = threadIdx.x;
    const int ti = t >> 4, tj = t & 15;

    float acc_ij = 0.f, acc_ji = 0.f;

    for (int k0 = 0; k0 < DIM; k0 += 64) {
        #pragma unroll
        for (int s = 0; s < 4; ++s) {
            int slot = s * 256 + t;          // 1024 float4 slots
            int tile = slot >> 8;            // 0:Qi 1:Ki 2:Qj 3:Kj
            int r    = (slot >> 4) & 15;
            int c4   = slot & 15;
            int grow = (tile < 2) ? (i0 + r) : (j0 + r);
            const float* src = (tile == 0 || tile == 2) ? QT : KT;
            float4 v = (grow < NR)
                ? *(const float4*)&src[grow * DIM + k0 + c4 * 4]
                : make_float4(0.f, 0.f, 0.f, 0.f);
            float* dst = (tile == 0) ? &Qi[r][c4 * 4]
                       : (tile == 1) ? &Ki[r][c4 * 4]
                       : (tile == 2) ? &Qj[r][c4 * 4] : &Kj[r][c4 * 4];
            *(float4*)dst = v;
        }
        __syncthreads();
        #pragma unroll 4
        for (int k = 0; k < 64; k += 4) {
            float4 qi = *(const float4*)&Qi[ti][k];
            float4 kj = *(const float4*)&Kj[tj][k];
            float4 qj = *(const float4*)&Qj[ti][k];
            float4 ki = *(const float4*)&Ki[tj][k];
            acc_ij += qi.x * kj.x + qi.y * kj.y + qi.z * kj.z + qi.w * kj.w;
            acc_ji += qj.x * ki.x + qj.y * ki.y + qj.z * ki.z + qj.w * ki.w;
        }
        __syncthreads();
    }

    Qi[ti][tj] = acc_ij;
    Ki[ti][tj] = acc_ji;
    __syncthreads();
    const float t_ij = Qi[tj][ti];   // G[i0+tj][j0+ti]
    const float t_ji = Ki[tj][ti];   // G[j0+tj][i0+ti]

    const int i1 = i0 + ti, j1 = j0 + tj;
    if (i1 < NR && j1 < NR) H[i1 * GSH + j1] = make_float2(acc_ij, t_ji);
    const int i2 = j0 + ti, j2 = i0 + tj;
    if (i2 < NR && j2 < NR) H[i2 * GSH + j2] = make_float2(acc_ji, t_ij);
}

// ---------------------------------------------------------------------------
// Kernel 3: fully wave-synchronous per-move pipeline — ZERO __syncthreads.
// 4096 blocks x 256 threads, 8 moves per block; move mv owned by half-wave mv,
// so every LDS producer/consumer pair lives in the same wave.
// NOTE: __launch_bounds__(256) ONLY — adding a min-waves arg (256,8) capped
// VGPRs at 32 and spilled the softmax register arrays to scratch (HBM-backed):
// FETCH 5.6->22 MB, WRITE 33.5->67 MB, +6 us. Register pressure needs ~40.
// ---------------------------------------------------------------------------
__global__ __launch_bounds__(256) void moves_kernel(
    const int* __restrict__ words, const int* __restrict__ rowsI,
    const int* __restrict__ colsI, const int* __restrict__ dirsI,
    const int* __restrict__ scoresI,
    const float2* __restrict__ H, const __hip_bfloat16* __restrict__ VT,
    const float* __restrict__ row_emb, const float* __restrict__ col_emb,
    const float* __restrict__ dir_emb, const float* __restrict__ score_emb,
    float* __restrict__ out)
{
    __shared__ float S[MPB][LW][17];     // 15x15 score matrix per move (padded)
    __shared__ int   rIdx[MPB][16];      // row indices per move
    __shared__ float csum[MPB][16];      // per-move column sums
    const int base = blockIdx.x * MPB;
    const int t = threadIdx.x;
    const int mv = t >> 5;               // half-wave id = move slot
    const int j  = t & 31;

    // rIdx: lanes j<15 of half-wave mv load move mv's own indices
    if (j < LW)
        rIdx[mv][j] = words[(base + mv) * LW + j] * LW + j;
    __builtin_amdgcn_wave_barrier();

    // -------- phase 1: 120 pair gathers per move over 32 lanes
    #pragma unroll
    for (int k = 0; k < 4; ++k) {
        int p = j + 32 * k;
        if (p < 120) {
            int lm = PAIR_LUT[p];
            int l = lm >> 4, m = lm & 15;
            int rl = rIdx[mv][l], rm = rIdx[mv][m];
            float2 hv = H[(size_t)rl * GSH + rm];
            S[mv][l][m] = hv.x;          // G[rl][rm] = S[l][m]
            S[mv][m][l] = hv.y;          // G[rm][rl] = S[m][l]
        }
    }
    __builtin_amdgcn_wave_barrier();

    // -------- phase 1b: row softmax (lane j handles row j of move mv)
    if (j < LW) {
        float s[LW];
        #pragma unroll
        for (int m = 0; m < LW; ++m) s[m] = S[mv][j][m];
        float mx = s[0];
        #pragma unroll
        for (int m = 1; m < LW; ++m) mx = fmaxf(mx, s[m]);
        float sum = 0.f;
        #pragma unroll
        for (int m = 0; m < LW; ++m) { s[m] = __expf(s[m] - mx); sum += s[m]; }
        float inv = 1.0f / sum;
        #pragma unroll
        for (int m = 0; m < LW; ++m) S[mv][j][m] = s[m] * inv;
    }
    __builtin_amdgcn_wave_barrier();

    // -------- column sums (lane j handles column j of move mv)
    if (j < LW) {
        float acc = 0.f;
        #pragma unroll
        for (int l = 0; l < LW; ++l) acc += S[mv][l][j];
        csum[mv][j] = acc;
    }
    __builtin_amdgcn_wave_barrier();

    // -------- phase 2: wave wv handles moves 2wv, 2wv+1 (wave-local data)
    const int wv = t >> 6;
    const int d0 = (t & 63) * 4;
    #pragma unroll
    for (int s2 = 0; s2 < 2; ++s2) {
        const int i = wv * 2 + s2;
        const int n = base + i;
        float wx = 0.f, wy = 0.f, wz = 0.f, ww = 0.f;
        #pragma unroll
        for (int m = 0; m < LW; ++m) {
            float c = csum[i][m];
            int r = rIdx[i][m];
            ushort4 vv = *(const ushort4*)((const unsigned short*)VT + (size_t)r * DIM + d0);
            wx += c * b2f(vv.x); wy += c * b2f(vv.y);
            wz += c * b2f(vv.z); ww += c * b2f(vv.w);
        }
        // uniform-address meta loads (1 line each, broadcast)
        float4 re = *(const float4*)&row_emb[rowsI[n] * DIM + d0];
        float4 ce = *(const float4*)&col_emb[colsI[n] * DIM + d0];
        float4 de = *(const float4*)&dir_emb[dirsI[n] * DIM + d0];
        float4 se = *(const float4*)&score_emb[min(scoresI[n], 99) * DIM + d0];
        float4 res;
        res.x = 2.f * wx + re.x + ce.x + de.x + se.x;
        res.y = 2.f * wy + re.y + ce.y + de.y + se.y;
        res.z = 2.f * wz + re.z + ce.z + de.z + se.z;
        res.w = 2.f * ww + re.w + ce.w + de.w + se.w;
        *(float4*)&out[(size_t)n * DIM + d0] = res;
    }
}

extern "C" void kernel_launch(void* const* d_in, const int* in_sizes, int n_in,
                              void* d_out, int out_size, void* d_ws, size_t ws_size,
                              hipStream_t stream)
{
    const int*   words      = (const int*)d_in[0];
    const int*   rowsI      = (const int*)d_in[1];
    const int*   colsI      = (const int*)d_in[2];
    const int*   dirsI      = (const int*)d_in[3];
    const int*   scoresI    = (const int*)d_in[4];
    const float* letter_emb = (const float*)d_in[5];
    const float* positional = (const float*)d_in[6];
    const float* Wq         = (const float*)d_in[7];
    const float* bq         = (const float*)d_in[8];
    const float* Wk         = (const float*)d_in[9];
    const float* bk         = (const float*)d_in[10];
    const float* Wv         = (const float*)d_in[11];
    const float* bv         = (const float*)d_in[12];
    const float* row_emb    = (const float*)d_in[13];
    const float* col_emb    = (const float*)d_in[14];
    const float* dir_emb    = (const float*)d_in[15];
    const float* score_emb  = (const float*)d_in[16];
    float* out = (float*)d_out;

    // workspace (bytes): QT f32[405*256] | KT f32[405*256] | H f2[405*408] | VT bf16[405*256]
    float*  QT = (float*)d_ws;
    float*  KT = QT + NR * DIM;
    float2* Hm = (float2*)(KT + NR * DIM);
    __hip_bfloat16* VT = (__hip_bfloat16*)((char*)Hm + (size_t)NR * GSH * sizeof(float2));

    qkv_tables<<<405, 256, 0, stream>>>(letter_emb, positional, Wq, bq, Wk, bk,
                                        Wv, bv, QT, KT, VT);
    h_matrix<<<351, 256, 0, stream>>>(QT, KT, Hm);
    moves_kernel<<<NMOV / MPB, 256, 0, stream>>>(words, rowsI, colsI, dirsI,
                                                 scoresI, Hm, VT, row_emb,
                                                 col_emb, dir_emb, score_emb,
                                                 out);
}

// Round 6
// 68.013 us; speedup vs baseline: 1.1357x; 1.0094x over previous
//
#include <hip/hip_runtime.h>
#include <hip/hip_bf16.h>

#define NMOV 32768
#define LW 15
#define DIM 256
#define NVOC 27
#define NR 405       // NVOC * LW distinct (letter, position) rows
#define GSH 408      // row stride of H in float2 units
#define MPB 8        // moves per block in moves_kernel

__device__ __forceinline__ float b2f(unsigned short u) {
    return __uint_as_float(((unsigned int)u) << 16);
}

// pair index p -> (l<<4 | m), l >= m, p = l(l+1)/2 + m
__device__ const unsigned char PAIR_LUT[120] = {
    0x00,
    0x10,0x11,
    0x20,0x21,0x22,
    0x30,0x31,0x32,0x33,
    0x40,0x41,0x42,0x43,0x44,
    0x50,0x51,0x52,0x53,0x54,0x55,
    0x60,0x61,0x62,0x63,0x64,0x65,0x66,
    0x70,0x71,0x72,0x73,0x74,0x75,0x76,0x77,
    0x80,0x81,0x82,0x83,0x84,0x85,0x86,0x87,0x88,
    0x90,0x91,0x92,0x93,0x94,0x95,0x96,0x97,0x98,0x99,
    0xA0,0xA1,0xA2,0xA3,0xA4,0xA5,0xA6,0xA7,0xA8,0xA9,0xAA,
    0xB0,0xB1,0xB2,0xB3,0xB4,0xB5,0xB6,0xB7,0xB8,0xB9,0xBA,0xBB,
    0xC0,0xC1,0xC2,0xC3,0xC4,0xC5,0xC6,0xC7,0xC8,0xC9,0xCA,0xCB,0xCC,
    0xD0,0xD1,0xD2,0xD3,0xD4,0xD5,0xD6,0xD7,0xD8,0xD9,0xDA,0xDB,0xDC,0xDD,
    0xE0,0xE1,0xE2,0xE3,0xE4,0xE5,0xE6,0xE7,0xE8,0xE9,0xEA,0xEB,0xEC,0xED,0xEE
};

// ---------------------------------------------------------------------------
// Kernel 1: QKV as tiled GEMM  [405 x 256] @ [256 x 768]^T-rows + bias.
// Grid 13 x 12 = 156 blocks: gy = 32-row tile of emb, gx = 64-col tile of
// (Wq|Wk|Wv) rows. A tile built from le+pos on the fly (coalesced); W tile
// staged TRANSPOSED into padded LDS (conflict-free b32 reads, coalesced
// global float4 loads). 256 threads; wave tm owns 8 output rows; thread
// computes 8 outputs.
// ---------------------------------------------------------------------------
__global__ __launch_bounds__(256) void qkv_gemm(
    const float* __restrict__ le, const float* __restrict__ pos,
    const float* __restrict__ Wq, const float* __restrict__ bq,
    const float* __restrict__ Wk, const float* __restrict__ bk,
    const float* __restrict__ Wv, const float* __restrict__ bv,
    float* __restrict__ QT, float* __restrict__ KT,
    __hip_bfloat16* __restrict__ VT)
{
    __shared__ float Ash[32][260];       // emb rows, b128-aligned stride
    __shared__ float Bsh[256][69];       // W transposed: Bsh[k][i] = W[nb+i][k]
    const int t  = threadIdx.x;
    const int gx = blockIdx.x % 12;
    const int gy = blockIdx.x / 12;
    const int r0 = gy * 32;
    const int mat = gx >> 2;             // 0=Q 1=K 2=V
    const int nb  = (gx & 3) * 64;       // col base within mat
    const float* W  = (mat == 0) ? Wq : (mat == 1) ? Wk : Wv;
    const float* bb = (mat == 0) ? bq : (mat == 1) ? bk : bv;

    // stage A (emb = le[c] + pos[l]), rows r0..r0+31, coalesced per wave
    #pragma unroll
    for (int s = 0; s < 8; ++s) {
        int slot = s * 256 + t;
        int row = slot >> 6, q4 = slot & 63;
        int r = r0 + row;
        float4 v = make_float4(0.f, 0.f, 0.f, 0.f);
        if (r < NR) {
            int c = r / 15, l = r - c * 15;
            float4 lv = *(const float4*)&le[c * DIM + q4 * 4];
            float4 pv = *(const float4*)&pos[l * DIM + q4 * 4];
            v = make_float4(lv.x + pv.x, lv.y + pv.y, lv.z + pv.z, lv.w + pv.w);
        }
        *(float4*)&Ash[row][q4 * 4] = v;
    }
    // stage B transposed: per wave row fixed, q4 = lane -> coalesced 1KB reads
    #pragma unroll
    for (int s = 0; s < 16; ++s) {
        int slot = s * 256 + t;
        int row = slot >> 6, q4 = slot & 63;
        float4 w4 = *(const float4*)&W[(nb + row) * DIM + q4 * 4];
        Bsh[q4 * 4 + 0][row] = w4.x;
        Bsh[q4 * 4 + 1][row] = w4.y;
        Bsh[q4 * 4 + 2][row] = w4.z;
        Bsh[q4 * 4 + 3][row] = w4.w;
    }
    __syncthreads();

    const int tn = t & 63, tm = t >> 6;
    float acc[8];
    #pragma unroll
    for (int rr = 0; rr < 8; ++rr) acc[rr] = 0.f;

    #pragma unroll 4
    for (int kq = 0; kq < 64; ++kq) {
        float4 a4[8];
        #pragma unroll
        for (int rr = 0; rr < 8; ++rr)      // broadcast reads (wave-uniform addr)
            a4[rr] = *(const float4*)&Ash[tm * 8 + rr][kq * 4];
        float b0 = Bsh[kq * 4 + 0][tn];     // lanes consecutive -> conflict-free
        float b1 = Bsh[kq * 4 + 1][tn];
        float b2 = Bsh[kq * 4 + 2][tn];
        float b3 = Bsh[kq * 4 + 3][tn];
        #pragma unroll
        for (int rr = 0; rr < 8; ++rr)
            acc[rr] += a4[rr].x * b0 + a4[rr].y * b1 + a4[rr].z * b2 + a4[rr].w * b3;
    }

    const float bias = bb[nb + tn];
    const int dcol = nb + tn;
    #pragma unroll
    for (int rr = 0; rr < 8; ++rr) {
        int r = r0 + tm * 8 + rr;
        if (r < NR) {
            float v = acc[rr] + bias;
            if (mat == 0)      QT[r * DIM + dcol] = v;
            else if (mat == 1) KT[r * DIM + dcol] = v;
            else               VT[r * DIM + dcol] = __float2bfloat16(v);
        }
    }
}

// ---------------------------------------------------------------------------
// Kernel 2: H[i][j] = { G[i][j], G[j][i] },  G[i][j] = QT[i,:].KT[j,:].
// Tile pairs (bi <= bj), 351 blocks, 16x16 tiles, BK=64.
// ---------------------------------------------------------------------------
__global__ __launch_bounds__(256) void h_matrix(
    const float* __restrict__ QT, const float* __restrict__ KT,
    float2* __restrict__ H)
{
    __shared__ float Qi[16][68], Ki[16][68], Qj[16][68], Kj[16][68];

    int rem = blockIdx.x, bi = 0, cnt = 26;
    while (rem >= cnt) { rem -= cnt; ++bi; --cnt; }
    const int bj = bi + rem;
    const int i0 = bi * 16, j0 = bj * 16;
    const int t = threadIdx.x;
    const int ti = t >> 4, tj = t & 15;

    float acc_ij = 0.f, acc_ji = 0.f;

    for (int k0 = 0; k0 < DIM; k0 += 64) {
        #pragma unroll
        for (int s = 0; s < 4; ++s) {
            int slot = s * 256 + t;          // 1024 float4 slots
            int tile = slot >> 8;            // 0:Qi 1:Ki 2:Qj 3:Kj
            int r    = (slot >> 4) & 15;
            int c4   = slot & 15;
            int grow = (tile < 2) ? (i0 + r) : (j0 + r);
            const float* src = (tile == 0 || tile == 2) ? QT : KT;
            float4 v = (grow < NR)
                ? *(const float4*)&src[grow * DIM + k0 + c4 * 4]
                : make_float4(0.f, 0.f, 0.f, 0.f);
            float* dst = (tile == 0) ? &Qi[r][c4 * 4]
                       : (tile == 1) ? &Ki[r][c4 * 4]
                       : (tile == 2) ? &Qj[r][c4 * 4] : &Kj[r][c4 * 4];
            *(float4*)dst = v;
        }
        __syncthreads();
        #pragma unroll 4
        for (int k = 0; k < 64; k += 4) {
            float4 qi = *(const float4*)&Qi[ti][k];
            float4 kj = *(const float4*)&Kj[tj][k];
            float4 qj = *(const float4*)&Qj[ti][k];
            float4 ki = *(const float4*)&Ki[tj][k];
            acc_ij += qi.x * kj.x + qi.y * kj.y + qi.z * kj.z + qi.w * kj.w;
            acc_ji += qj.x * ki.x + qj.y * ki.y + qj.z * ki.z + qj.w * ki.w;
        }
        __syncthreads();
    }

    Qi[ti][tj] = acc_ij;
    Ki[ti][tj] = acc_ji;
    __syncthreads();
    const float t_ij = Qi[tj][ti];   // G[i0+tj][j0+ti]
    const float t_ji = Ki[tj][ti];   // G[j0+tj][i0+ti]

    const int i1 = i0 + ti, j1 = j0 + tj;
    if (i1 < NR && j1 < NR) H[i1 * GSH + j1] = make_float2(acc_ij, t_ji);
    const int i2 = j0 + ti, j2 = i0 + tj;
    if (i2 < NR && j2 < NR) H[i2 * GSH + j2] = make_float2(acc_ji, t_ij);
}

// ---------------------------------------------------------------------------
// Kernel 3: wave-synchronous per-move pipeline, ZERO __syncthreads, with
// explicit load batching:
//  - H pair gathers land in registers first (one vmcnt wait for all 4)
//  - VT rows for move A prefetched as ushort4[15] BEFORE softmax (in-order
//    vmcnt keeps them in flight while H data is consumed)
//  - move B's 15 VT loads + 4 epilogue loads batched the same way.
// NOTE: __launch_bounds__(256) ONLY — a (256,8) min-waves arg caps VGPR at 32
// and spills softmax arrays to scratch (HBM): FETCH 5.6->22MB, WRITE 2x.
// ---------------------------------------------------------------------------
__global__ __launch_bounds__(256) void moves_kernel(
    const int* __restrict__ words, const int* __restrict__ rowsI,
    const int* __restrict__ colsI, const int* __restrict__ dirsI,
    const int* __restrict__ scoresI,
    const float2* __restrict__ H, const __hip_bfloat16* __restrict__ VT,
    const float* __restrict__ row_emb, const float* __restrict__ col_emb,
    const float* __restrict__ dir_emb, const float* __restrict__ score_emb,
    float* __restrict__ out)
{
    __shared__ float S[MPB][LW][17];     // 15x15 score matrix per move (padded)
    __shared__ int   rIdx[MPB][16];      // row indices per move
    __shared__ float csum[MPB][16];      // per-move column sums
    const int base = blockIdx.x * MPB;
    const int t = threadIdx.x;
    const int mv = t >> 5;               // half-wave id = move slot
    const int j  = t & 31;

    if (j < LW)
        rIdx[mv][j] = words[(base + mv) * LW + j] * LW + j;
    __builtin_amdgcn_wave_barrier();

    const int wv = t >> 6;
    const int d0 = (t & 63) * 4;
    const unsigned short* VT16 = (const unsigned short*)VT;

    // -------- phase 1: H pair gathers into registers (4 independent loads)
    float2 hv[4];
    int ll[4], mm[4];
    #pragma unroll
    for (int k = 0; k < 4; ++k) {
        int p = j + 32 * k;
        if (p < 120) {
            int lm = PAIR_LUT[p];
            ll[k] = lm >> 4; mm[k] = lm & 15;
            int rl = rIdx[mv][ll[k]], rm = rIdx[mv][mm[k]];
            hv[k] = H[(size_t)rl * GSH + rm];
        }
    }

    // -------- prefetch VT rows for move A (stays in flight during softmax)
    const int iA = wv * 2, nA = base + iA;
    ushort4 vvA[LW];
    #pragma unroll
    for (int m = 0; m < LW; ++m) {
        int r = rIdx[iA][m];
        vvA[m] = *(const ushort4*)(VT16 + (size_t)r * DIM + d0);
    }
    // epilogue loads for move A (index load then table row; independent of S)
    float4 reA = *(const float4*)&row_emb[rowsI[nA] * DIM + d0];
    float4 ceA = *(const float4*)&col_emb[colsI[nA] * DIM + d0];
    float4 deA = *(const float4*)&dir_emb[dirsI[nA] * DIM + d0];
    float4 seA = *(const float4*)&score_emb[min(scoresI[nA], 99) * DIM + d0];

    // scatter H results to S (waits only the 4 hv loads; vvA stays in flight)
    #pragma unroll
    for (int k = 0; k < 4; ++k) {
        int p = j + 32 * k;
        if (p < 120) {
            S[mv][ll[k]][mm[k]] = hv[k].x;
            S[mv][mm[k]][ll[k]] = hv[k].y;
        }
    }
    __builtin_amdgcn_wave_barrier();

    // -------- phase 1b: row softmax (lane j handles row j of move mv)
    if (j < LW) {
        float s[LW];
        #pragma unroll
        for (int m = 0; m < LW; ++m) s[m] = S[mv][j][m];
        float mx = s[0];
        #pragma unroll
        for (int m = 1; m < LW; ++m) mx = fmaxf(mx, s[m]);
        float sum = 0.f;
        #pragma unroll
        for (int m = 0; m < LW; ++m) { s[m] = __expf(s[m] - mx); sum += s[m]; }
        float inv = 1.0f / sum;
        #pragma unroll
        for (int m = 0; m < LW; ++m) S[mv][j][m] = s[m] * inv;
    }
    __builtin_amdgcn_wave_barrier();

    // -------- column sums (lane j handles column j of move mv)
    if (j < LW) {
        float acc = 0.f;
        #pragma unroll
        for (int l = 0; l < LW; ++l) acc += S[mv][l][j];
        csum[mv][j] = acc;
    }
    __builtin_amdgcn_wave_barrier();

    // -------- phase 2 move A: vvA + epilogue already in flight
    {
        float wx = 0.f, wy = 0.f, wz = 0.f, ww = 0.f;
        #pragma unroll
        for (int m = 0; m < LW; ++m) {
            float c = csum[iA][m];
            wx += c * b2f(vvA[m].x); wy += c * b2f(vvA[m].y);
            wz += c * b2f(vvA[m].z); ww += c * b2f(vvA[m].w);
        }
        float4 res;
        res.x = 2.f * wx + reA.x + ceA.x + deA.x + seA.x;
        res.y = 2.f * wy + reA.y + ceA.y + deA.y + seA.y;
        res.z = 2.f * wz + reA.z + ceA.z + deA.z + seA.z;
        res.w = 2.f * ww + reA.w + ceA.w + deA.w + seA.w;
        *(float4*)&out[(size_t)nA * DIM + d0] = res;
    }

    // -------- phase 2 move B: batched loads (one wait for all 19)
    {
        const int iB = wv * 2 + 1, nB = base + iB;
        ushort4 vvB[LW];
        #pragma unroll
        for (int m = 0; m < LW; ++m) {
            int r = rIdx[iB][m];
            vvB[m] = *(const ushort4*)(VT16 + (size_t)r * DIM + d0);
        }
        float4 reB = *(const float4*)&row_emb[rowsI[nB] * DIM + d0];
        float4 ceB = *(const float4*)&col_emb[colsI[nB] * DIM + d0];
        float4 deB = *(const float4*)&dir_emb[dirsI[nB] * DIM + d0];
        float4 seB = *(const float4*)&score_emb[min(scoresI[nB], 99) * DIM + d0];

        float wx = 0.f, wy = 0.f, wz = 0.f, ww = 0.f;
        #pragma unroll
        for (int m = 0; m < LW; ++m) {
            float c = csum[iB][m];
            wx += c * b2f(vvB[m].x); wy += c * b2f(vvB[m].y);
            wz += c * b2f(vvB[m].z); ww += c * b2f(vvB[m].w);
        }
        float4 res;
        res.x = 2.f * wx + reB.x + ceB.x + deB.x + seB.x;
        res.y = 2.f * wy + reB.y + ceB.y + deB.y + seB.y;
        res.z = 2.f * wz + reB.z + ceB.z + deB.z + seB.z;
        res.w = 2.f * ww + reB.w + ceB.w + deB.w + seB.w;
        *(float4*)&out[(size_t)nB * DIM + d0] = res;
    }
}

extern "C" void kernel_launch(void* const* d_in, const int* in_sizes, int n_in,
                              void* d_out, int out_size, void* d_ws, size_t ws_size,
                              hipStream_t stream)
{
    const int*   words      = (const int*)d_in[0];
    const int*   rowsI      = (const int*)d_in[1];
    const int*   colsI      = (const int*)d_in[2];
    const int*   dirsI      = (const int*)d_in[3];
    const int*   scoresI    = (const int*)d_in[4];
    const float* letter_emb = (const float*)d_in[5];
    const float* positional = (const float*)d_in[6];
    const float* Wq         = (const float*)d_in[7];
    const float* bq         = (const float*)d_in[8];
    const float* Wk         = (const float*)d_in[9];
    const float* bk         = (const float*)d_in[10];
    const float* Wv         = (const float*)d_in[11];
    const float* bv         = (const float*)d_in[12];
    const float* row_emb    = (const float*)d_in[13];
    const float* col_emb    = (const float*)d_in[14];
    const float* dir_emb    = (const float*)d_in[15];
    const float* score_emb  = (const float*)d_in[16];
    float* out = (float*)d_out;

    // workspace (bytes): QT f32[405*256] | KT f32[405*256] | H f2[405*408] | VT bf16[405*256]
    float*  QT = (float*)d_ws;
    float*  KT = QT + NR * DIM;
    float2* Hm = (float2*)(KT + NR * DIM);
    __hip_bfloat16* VT = (__hip_bfloat16*)((char*)Hm + (size_t)NR * GSH * sizeof(float2));

    qkv_gemm<<<156, 256, 0, stream>>>(letter_emb, positional, Wq, bq, Wk, bk,
                                      Wv, bv, QT, KT, VT);
    h_matrix<<<351, 256, 0, stream>>>(QT, KT, Hm);
    moves_kernel<<<NMOV / MPB, 256, 0, stream>>>(words, rowsI, colsI, dirsI,
                                                 scoresI, Hm, VT, row_emb,
                                                 col_emb, dir_emb, score_emb,
                                                 out);
}